// Round 7
// baseline (917.772 us; speedup 1.0000x reference)
//
#include <hip/hip_runtime.h>
#include <hip/hip_bf16.h>

#define DEVI __device__ __forceinline__

typedef __bf16 bfrag __attribute__((ext_vector_type(8)));
typedef unsigned short us8 __attribute__((ext_vector_type(8)));
typedef float f32x4 __attribute__((ext_vector_type(4)));
typedef unsigned short ushort_t;

static constexpr int NB  = 16;
static constexpr int NH  = 8;
static constexpr int DIM = 1024;
static constexpr int DQh = 128;
static constexpr int ST  = 1024;
static constexpr int SM  = 2048;
static constexpr float INV_SCALE = 0.29730177875068026f; // 1 / 128^0.25
static constexpr float LN_EPS = 1e-5f;

DEVI ushort_t f2bf(float f) {
  __hip_bfloat16 h = __float2bfloat16(f);
  return __builtin_bit_cast(ushort_t, h);
}
DEVI float bf2f(ushort_t u) {
  return __bfloat162float(__builtin_bit_cast(__hip_bfloat16, u));
}
DEVI bfrag ldfrag(const ushort_t* p) {
  return __builtin_bit_cast(bfrag, *(const us8*)p);
}
DEVI void gl16(const ushort_t* g, ushort_t* l) {
  __builtin_amdgcn_global_load_lds(
      (const __attribute__((address_space(1))) void*)g,
      (__attribute__((address_space(3))) void*)l, 16, 0, 0);
}

enum { ST_BF16 = 0, ST_SWISH = 1 };

// ---------------------------------------------------------------------------
// K/V projection GEMM with fused wave-local softmax (R5 structure).
// ---------------------------------------------------------------------------
__global__ __launch_bounds__(256, 4)
void gemm_qkv(const ushort_t* __restrict__ A, const ushort_t* __restrict__ Bt,
              ushort_t* __restrict__ P0, ushort_t* __restrict__ P1,
              int M, int N, int K, int logS, int smflags)
{
  __shared__ ushort_t As[128][32];
  __shared__ ushort_t Bs[128][32];
  const int tid = threadIdx.x;
  int bx = blockIdx.x, by = blockIdx.y;
  {
    const int gx = gridDim.x;
    const int nwg = gx * gridDim.y;
    int bid = by * gx + bx;
    if ((nwg & 7) == 0) bid = (bid & 7) * (nwg >> 3) + (bid >> 3);  // XCD swizzle
    bx = bid % gx; by = bid / gx;
  }
  const int m0 = by * 128, n0 = bx * 128;

  const int lane = tid & 63;
  const int w = tid >> 6;
  const int wr = w * 32;
  const int frow = lane & 15;
  const int q = lane >> 4;

  const int grow = lane >> 2;
  const int gk = ((lane & 3) ^ ((lane >> 3) & 3)) * 8;
  const ushort_t* Ag = A + (long)(m0 + w * 32 + grow) * K + gk;
  const ushort_t* Bg = Bt + (long)(n0 + w * 32 + grow) * K + gk;

  f32x4 acc[2][8];
  #pragma unroll
  for (int i = 0; i < 2; ++i)
    #pragma unroll
    for (int j = 0; j < 8; ++j) acc[i][j] = f32x4{0.f, 0.f, 0.f, 0.f};

  const int kqs = (frow >> 1) & 3;
  for (int k0 = 0; k0 < K; k0 += 32) {
    __syncthreads();
    gl16(Ag + k0,                &As[w * 32][0]);
    gl16(Ag + k0 + (long)16 * K, &As[w * 32 + 16][0]);
    gl16(Bg + k0,                &Bs[w * 32][0]);
    gl16(Bg + k0 + (long)16 * K, &Bs[w * 32 + 16][0]);
    __syncthreads();
    const int kq = (q ^ kqs) * 8;
    const bfrag af0 = ldfrag(&As[wr + frow][kq]);
    const bfrag af1 = ldfrag(&As[wr + 16 + frow][kq]);
    #pragma unroll
    for (int j = 0; j < 8; ++j) {
      const bfrag bf = ldfrag(&Bs[j * 16 + frow][kq]);
      acc[0][j] = __builtin_amdgcn_mfma_f32_16x16x32_bf16(af0, bf, acc[0][j], 0, 0, 0);
      acc[1][j] = __builtin_amdgcn_mfma_f32_16x16x32_bf16(af1, bf, acc[1][j], 0, 0, 0);
    }
  }

  const int sel = n0 >> 10;  // block-uniform
  const bool dosm = (smflags >> sel) & 1;
  const int h = (n0 >> 7) & 7;
  ushort_t* __restrict__ Bq = (sel == 0) ? P0 : P1;
  const int S = 1 << logS;
  #pragma unroll
  for (int i = 0; i < 2; ++i) {
    #pragma unroll
    for (int e = 0; e < 4; ++e) {
      const int gm = m0 + wr + i * 16 + q * 4 + e;
      const int b = gm >> logS, s = gm & (S - 1);
      float v[8];
      #pragma unroll
      for (int j = 0; j < 8; ++j) v[j] = acc[i][j][e];
      if (dosm) {
        #pragma unroll
        for (int j = 0; j < 8; ++j) v[j] *= INV_SCALE;
        float mx = v[0];
        #pragma unroll
        for (int j = 1; j < 8; ++j) mx = fmaxf(mx, v[j]);
        mx = fmaxf(mx, __shfl_xor(mx, 1));
        mx = fmaxf(mx, __shfl_xor(mx, 2));
        mx = fmaxf(mx, __shfl_xor(mx, 4));
        mx = fmaxf(mx, __shfl_xor(mx, 8));
        float sm = 0.f;
        #pragma unroll
        for (int j = 0; j < 8; ++j) { v[j] = __expf(v[j] - mx); sm += v[j]; }
        sm += __shfl_xor(sm, 1);
        sm += __shfl_xor(sm, 2);
        sm += __shfl_xor(sm, 4);
        sm += __shfl_xor(sm, 8);
        const float inv = 1.0f / sm;
        #pragma unroll
        for (int j = 0; j < 8; ++j) v[j] *= inv;
      }
      ushort_t* rowp = Bq + ((long)(h * 16 + b) * S + (long)s) * 128;
      #pragma unroll
      for (int j = 0; j < 8; ++j) rowp[j * 16 + frow] = f2bf(v[j]);
    }
  }
}

// ---------------------------------------------------------------------------
// Fused Q path (R6): scores -> wave-local softmax -> P@A -> scramble store.
// ---------------------------------------------------------------------------
template<bool MASKED>
__global__ __launch_bounds__(256, 3)
void fused_qa(const ushort_t* __restrict__ A, const ushort_t* __restrict__ Wq,
              const ushort_t* __restrict__ AT, ushort_t* __restrict__ Out)
{
  __shared__ ushort_t As[128][32];
  __shared__ ushort_t Bs[128][32];
  __shared__ ushort_t Ps[4][32][128];
  const int tid = threadIdx.x;
  int h = blockIdx.x, by = blockIdx.y;
  {
    const int gx = gridDim.x;
    const int nwg = gx * gridDim.y;
    int bid = by * gx + h;
    if ((nwg & 7) == 0) bid = (bid & 7) * (nwg >> 3) + (bid >> 3);
    h = bid % gx; by = bid / gx;
  }
  const int m0 = by * 128;

  const int lane = tid & 63;
  const int w = tid >> 6;
  const int wr = w * 32;
  const int frow = lane & 15;
  const int q = lane >> 4;

  const int grow = lane >> 2;
  const int gk = ((lane & 3) ^ ((lane >> 3) & 3)) * 8;
  const ushort_t* Ag = A + (long)(m0 + w * 32 + grow) * 1024 + gk;
  const ushort_t* Bg = Wq + (long)(h * 128 + w * 32 + grow) * 1024 + gk;

  f32x4 acc[2][8];
  #pragma unroll
  for (int i = 0; i < 2; ++i)
    #pragma unroll
    for (int j = 0; j < 8; ++j) acc[i][j] = f32x4{0.f, 0.f, 0.f, 0.f};

  const int kqs = (frow >> 1) & 3;
  for (int k0 = 0; k0 < 1024; k0 += 32) {
    __syncthreads();
    gl16(Ag + k0,             &As[w * 32][0]);
    gl16(Ag + k0 + 16 * 1024, &As[w * 32 + 16][0]);
    gl16(Bg + k0,             &Bs[w * 32][0]);
    gl16(Bg + k0 + 16 * 1024, &Bs[w * 32 + 16][0]);
    __syncthreads();
    const int kq = (q ^ kqs) * 8;
    const bfrag af0 = ldfrag(&As[wr + frow][kq]);
    const bfrag af1 = ldfrag(&As[wr + 16 + frow][kq]);
    #pragma unroll
    for (int j = 0; j < 8; ++j) {
      const bfrag bf = ldfrag(&Bs[j * 16 + frow][kq]);
      acc[0][j] = __builtin_amdgcn_mfma_f32_16x16x32_bf16(af0, bf, acc[0][j], 0, 0, 0);
      acc[1][j] = __builtin_amdgcn_mfma_f32_16x16x32_bf16(af1, bf, acc[1][j], 0, 0, 0);
    }
  }

  // softmax + write P to per-wave swizzled LDS
  #pragma unroll
  for (int i = 0; i < 2; ++i) {
    #pragma unroll
    for (int e = 0; e < 4; ++e) {
      const int row32 = i * 16 + q * 4 + e;
      const int srow = (m0 + wr + row32) & (ST - 1);
      float v[8];
      #pragma unroll
      for (int j = 0; j < 8; ++j) {
        v[j] = acc[i][j][e] * INV_SCALE;
        if (MASKED && (j * 16 + frow) > srow) v[j] = -3.0e38f;
      }
      float mx = v[0];
      #pragma unroll
      for (int j = 1; j < 8; ++j) mx = fmaxf(mx, v[j]);
      mx = fmaxf(mx, __shfl_xor(mx, 1));
      mx = fmaxf(mx, __shfl_xor(mx, 2));
      mx = fmaxf(mx, __shfl_xor(mx, 4));
      mx = fmaxf(mx, __shfl_xor(mx, 8));
      float sm = 0.f;
      #pragma unroll
      for (int j = 0; j < 8; ++j) { v[j] = __expf(v[j] - mx); sm += v[j]; }
      sm += __shfl_xor(sm, 1);
      sm += __shfl_xor(sm, 2);
      sm += __shfl_xor(sm, 4);
      sm += __shfl_xor(sm, 8);
      const float inv = 1.0f / sm;
      const int sw = (row32 >> 1) & 3;
      ushort_t* pr = &Ps[w][row32][0];
      #pragma unroll
      for (int j = 0; j < 8; ++j) {
        const int c = j * 16 + frow;
        const int pos = (c & ~31) | ((((c >> 3) & 3) ^ sw) << 3) | (c & 7);
        pr[pos] = f2bf(v[j] * inv);
      }
    }
  }

  // stage 2: P(128x128) @ AT_z(128e x 128d, [N][K] form)
  f32x4 acc2[2][8];
  #pragma unroll
  for (int i = 0; i < 2; ++i)
    #pragma unroll
    for (int j = 0; j < 8; ++j) acc2[i][j] = f32x4{0.f, 0.f, 0.f, 0.f};

  const ushort_t* Atg = AT + (long)((h << 4) + (m0 >> 10)) * 16384 +
                        (long)(w * 32 + grow) * 128 + gk;
  for (int d0 = 0; d0 < 128; d0 += 32) {
    __syncthreads();
    gl16(Atg + d0,            &Bs[w * 32][0]);
    gl16(Atg + d0 + 16 * 128, &Bs[w * 32 + 16][0]);
    __syncthreads();
    const int kq = (q ^ kqs) * 8;
    const bfrag af0 = ldfrag(&Ps[w][frow][d0 + kq]);
    const bfrag af1 = ldfrag(&Ps[w][16 + frow][d0 + kq]);
    #pragma unroll
    for (int j = 0; j < 8; ++j) {
      const bfrag bf = ldfrag(&Bs[j * 16 + frow][kq]);
      acc2[0][j] = __builtin_amdgcn_mfma_f32_16x16x32_bf16(af0, bf, acc2[0][j], 0, 0, 0);
      acc2[1][j] = __builtin_amdgcn_mfma_f32_16x16x32_bf16(af1, bf, acc2[1][j], 0, 0, 0);
    }
  }

  ushort_t* ob = Out + (long)(m0 >> 10) * (ST * DIM);
  #pragma unroll
  for (int i = 0; i < 2; ++i) {
    #pragma unroll
    for (int e = 0; e < 4; ++e) {
      const int srow = (m0 + wr + i * 16 + q * 4 + e) & (ST - 1);
      ushort_t* orow = ob + (long)(h * 128 + (srow >> 3)) * DIM + (srow & 7) * 128;
      #pragma unroll
      for (int j = 0; j < 8; ++j)
        orow[j * 16 + frow] = f2bf(acc2[i][j][e]);
    }
  }
}

// ---------------------------------------------------------------------------
// Row-complete output GEMM with fused residual + LayerNorm.
// C = A[M][K] x Bt[1024][K]^T, tile 64 rows x all 1024 cols, 8 waves
// (wave w owns cols [w*128, w*128+128)). Epilogue: val += Res (f32);
// per-row mean/var via in-wave shfl + LDS cross-wave combine; write
// normalized result as f32 (Yf) and optionally bf16 (Yb).
// ---------------------------------------------------------------------------
template<bool WRITE_BF16>
__global__ __launch_bounds__(512, 2)
void gemm_ln(const ushort_t* __restrict__ A, const ushort_t* __restrict__ Bt,
             const float* __restrict__ Res, const float* __restrict__ G,
             const float* __restrict__ Bias,
             ushort_t* __restrict__ Yb, float* __restrict__ Yf, int K)
{
  __shared__ ushort_t As[64][32];
  __shared__ ushort_t Bs[1024][32];
  __shared__ float red[64][8][2];
  const int tid = threadIdx.x;
  int bid = blockIdx.x;
  {
    const int nwg = gridDim.x;  // 256, divisible by 8
    bid = (bid & 7) * (nwg >> 3) + (bid >> 3);
  }
  const int m0 = bid * 64;

  const int lane = tid & 63;
  const int w = tid >> 6;       // 0..7
  const int frow = lane & 15;
  const int q = lane >> 4;

  const int grow = lane >> 2;
  const int gk = ((lane & 3) ^ ((lane >> 3) & 3)) * 8;
  const ushort_t* Ag = A + (long)(m0 + (w & 3) * 16 + grow) * K + gk;
  const ushort_t* Bg = Bt + (long)(w * 128 + grow) * K + gk;

  f32x4 acc[4][8];
  #pragma unroll
  for (int i = 0; i < 4; ++i)
    #pragma unroll
    for (int j = 0; j < 8; ++j) acc[i][j] = f32x4{0.f, 0.f, 0.f, 0.f};

  const int kqs = (frow >> 1) & 3;
  for (int k0 = 0; k0 < K; k0 += 32) {
    __syncthreads();
    if (w < 4) gl16(Ag + k0, &As[w * 16][0]);
    #pragma unroll
    for (int c = 0; c < 8; ++c)
      gl16(Bg + (long)(c * 16) * K + k0, &Bs[w * 128 + c * 16][0]);
    __syncthreads();
    const int kq = (q ^ kqs) * 8;
    bfrag af[4];
    #pragma unroll
    for (int i = 0; i < 4; ++i) af[i] = ldfrag(&As[i * 16 + frow][kq]);
    #pragma unroll
    for (int j = 0; j < 8; ++j) {
      const bfrag bf = ldfrag(&Bs[w * 128 + j * 16 + frow][kq]);
      #pragma unroll
      for (int i = 0; i < 4; ++i)
        acc[i][j] = __builtin_amdgcn_mfma_f32_16x16x32_bf16(af[i], bf, acc[i][j], 0, 0, 0);
    }
  }

  // ---- epilogue: residual add + per-row partial sums ----
  const int gnb = w * 128;
  #pragma unroll
  for (int i = 0; i < 4; ++i) {
    #pragma unroll
    for (int e = 0; e < 4; ++e) {
      const int r = i * 16 + q * 4 + e;
      const float* rr = Res + (long)(m0 + r) * 1024 + gnb;
      float s = 0.f, sq = 0.f;
      #pragma unroll
      for (int j = 0; j < 8; ++j) {
        float v = acc[i][j][e] + rr[j * 16 + frow];
        acc[i][j][e] = v;
        s += v; sq += v * v;
      }
      s += __shfl_xor(s, 1);  sq += __shfl_xor(sq, 1);
      s += __shfl_xor(s, 2);  sq += __shfl_xor(sq, 2);
      s += __shfl_xor(s, 4);  sq += __shfl_xor(sq, 4);
      s += __shfl_xor(s, 8);  sq += __shfl_xor(sq, 8);
      if (frow == 0) { red[r][w][0] = s; red[r][w][1] = sq; }
    }
  }
  __syncthreads();

  float gv[8], bv[8];
  #pragma unroll
  for (int j = 0; j < 8; ++j) {
    gv[j] = G[gnb + j * 16 + frow];
    bv[j] = Bias[gnb + j * 16 + frow];
  }
  #pragma unroll
  for (int i = 0; i < 4; ++i) {
    #pragma unroll
    for (int e = 0; e < 4; ++e) {
      const int r = i * 16 + q * 4 + e;
      float s = 0.f, sq = 0.f;
      #pragma unroll
      for (int ww = 0; ww < 8; ++ww) { s += red[r][ww][0]; sq += red[r][ww][1]; }
      const float mean = s * (1.0f / 1024.0f);
      const float var  = sq * (1.0f / 1024.0f) - mean * mean;
      const float rstd = rsqrtf(var + LN_EPS);
      float* yr = Yf + (long)(m0 + r) * 1024 + gnb;
      ushort_t* ybr = WRITE_BF16 ? (Yb + (long)(m0 + r) * 1024 + gnb) : nullptr;
      #pragma unroll
      for (int j = 0; j < 8; ++j) {
        const float o = (acc[i][j][e] - mean) * rstd * gv[j] + bv[j];
        yr[j * 16 + frow] = o;
        if (WRITE_BF16) ybr[j * 16 + frow] = f2bf(o);
      }
    }
  }
}

// ---------------------------------------------------------------------------
// 128x128-tile bf16 GEMM (m97 structure), 2x2 waves. bf16 stores (+swish).
// ---------------------------------------------------------------------------
template<int STORE>
__global__ __launch_bounds__(256, 2)
void gemm_bb(const ushort_t* __restrict__ A, const ushort_t* __restrict__ Bt,
             ushort_t* __restrict__ P0, int M, int N, int K)
{
  __shared__ ushort_t As[128][32];
  __shared__ ushort_t Bs[128][32];
  const int tid = threadIdx.x;
  int bx = blockIdx.x, by = blockIdx.y;
  {
    const int gx = gridDim.x;
    const int nwg = gx * gridDim.y;
    int bid = by * gx + bx;
    if ((nwg & 7) == 0) bid = (bid & 7) * (nwg >> 3) + (bid >> 3);
    bx = bid % gx; by = bid / gx;
  }
  const int m0 = by * 128, n0 = bx * 128;

  const int lane = tid & 63;
  const int w = tid >> 6;
  const int wr = (w >> 1) * 64, wc = (w & 1) * 64;
  const int frow = lane & 15;
  const int q = lane >> 4;

  const int grow = lane >> 2;
  const int gk = ((lane & 3) ^ ((lane >> 3) & 3)) * 8;
  const ushort_t* Ag = A + (long)(m0 + w * 32 + grow) * K + gk;
  const ushort_t* Bg = Bt + (long)(n0 + w * 32 + grow) * K + gk;

  f32x4 acc[4][4];
  #pragma unroll
  for (int i = 0; i < 4; ++i)
    #pragma unroll
    for (int j = 0; j < 4; ++j) acc[i][j] = f32x4{0.f, 0.f, 0.f, 0.f};

  const int kqs = (frow >> 1) & 3;
  for (int k0 = 0; k0 < K; k0 += 32) {
    __syncthreads();
    gl16(Ag + k0,                &As[w * 32][0]);
    gl16(Ag + k0 + (long)16 * K, &As[w * 32 + 16][0]);
    gl16(Bg + k0,                &Bs[w * 32][0]);
    gl16(Bg + k0 + (long)16 * K, &Bs[w * 32 + 16][0]);
    __syncthreads();
    const int kq = (q ^ kqs) * 8;
    bfrag af[4], bf[4];
    #pragma unroll
    for (int i = 0; i < 4; ++i) af[i] = ldfrag(&As[wr + i * 16 + frow][kq]);
    #pragma unroll
    for (int j = 0; j < 4; ++j) bf[j] = ldfrag(&Bs[wc + j * 16 + frow][kq]);
    #pragma unroll
    for (int i = 0; i < 4; ++i)
      #pragma unroll
      for (int j = 0; j < 4; ++j)
        acc[i][j] = __builtin_amdgcn_mfma_f32_16x16x32_bf16(af[i], bf[j], acc[i][j], 0, 0, 0);
  }

  const int rb = q * 4;
  #pragma unroll
  for (int i = 0; i < 4; ++i) {
    #pragma unroll
    for (int j = 0; j < 4; ++j) {
      #pragma unroll
      for (int e = 0; e < 4; ++e) {
        const int gm = m0 + wr + i * 16 + rb + e;
        const int gn = n0 + wc + j * 16 + frow;
        float val = acc[i][j][e];
        if constexpr (STORE == ST_SWISH) val = val / (1.0f + __expf(-val));
        P0[(long)gm * N + gn] = f2bf(val);
      }
    }
  }
}

// ---------------------------------------------------------------------------
// Split-S K^T·V: P[ch][z][e][d] = sum_{s in chunk} V[z][s][e]*softK[z][s][d]
// ---------------------------------------------------------------------------
__global__ __launch_bounds__(256, 2)
void gemm_ktv(const ushort_t* __restrict__ Kp, const ushort_t* __restrict__ Vp,
              float* __restrict__ P, int S, int SC)
{
  __shared__ ushort_t As[128][40];
  __shared__ ushort_t Bs[128][40];
  const int tid = threadIdx.x;
  const int z = blockIdx.x;
  const int ch = blockIdx.y;
  const long base = ((long)z * S + (long)ch * SC) * DQh;
  const ushort_t* Vb = Vp + base;
  const ushort_t* Kb = Kp + base;
  const int lane = tid & 63;
  const int wr = ((tid >> 6) >> 1) * 64, wc = ((tid >> 6) & 1) * 64;
  const int frow = lane & 15, fk = (lane >> 4) * 8;
  const int c = tid & 127;
  const int sr0 = tid >> 7;

  f32x4 acc[4][4];
  #pragma unroll
  for (int i = 0; i < 4; ++i)
    #pragma unroll
    for (int j = 0; j < 4; ++j) acc[i][j] = f32x4{0.f, 0.f, 0.f, 0.f};

  for (int s0 = 0; s0 < SC; s0 += 32) {
    __syncthreads();
    #pragma unroll
    for (int p = 0; p < 16; ++p) {
      const int sr = sr0 + p * 2;
      As[c][sr] = Vb[(long)(s0 + sr) * DQh + c];
      Bs[c][sr] = Kb[(long)(s0 + sr) * DQh + c];
    }
    __syncthreads();
    bfrag af[4], bfv[4];
    #pragma unroll
    for (int i = 0; i < 4; ++i) af[i]  = ldfrag(&As[wr + i * 16 + frow][fk]);
    #pragma unroll
    for (int j = 0; j < 4; ++j) bfv[j] = ldfrag(&Bs[wc + j * 16 + frow][fk]);
    #pragma unroll
    for (int i = 0; i < 4; ++i)
      #pragma unroll
      for (int j = 0; j < 4; ++j)
        acc[i][j] = __builtin_amdgcn_mfma_f32_16x16x32_bf16(af[i], bfv[j], acc[i][j], 0, 0, 0);
  }
  float* Pz = P + ((long)ch * 128 + z) * 16384;
  const int rb = (lane >> 4) * 4;
  #pragma unroll
  for (int i = 0; i < 4; ++i)
    #pragma unroll
    for (int j = 0; j < 4; ++j)
      #pragma unroll
      for (int e = 0; e < 4; ++e)
        Pz[(long)(wr + i * 16 + rb + e) * 128 + (wc + j * 16 + frow)] = acc[i][j][e];
}

__global__ __launch_bounds__(256)
void ktv_reduce(const float* __restrict__ P, ushort_t* __restrict__ AT, int nch)
{
  const long i = ((long)blockIdx.x * 256 + threadIdx.x) * 4;
  float4 s = *(const float4*)(P + i);
  for (int c = 1; c < nch; ++c) {
    const float4 v = *(const float4*)(P + (long)c * 2097152 + i);
    s.x += v.x; s.y += v.y; s.z += v.z; s.w += v.w;
  }
  ushort4 o = make_ushort4(f2bf(s.x), f2bf(s.y), f2bf(s.z), f2bf(s.w));
  *(ushort4*)(AT + i) = o;
}

__global__ __launch_bounds__(256)
void transpose_cast(const float* __restrict__ W, ushort_t* __restrict__ Wt)
{
  __shared__ float tile[32][33];
  const int z = blockIdx.z;
  const int kb = blockIdx.y * 32;
  const int nb = blockIdx.x * 32;
  const float* src = W + (long)z * DIM * DQh;
  ushort_t* dst = Wt + (long)z * DIM * DQh;
  const int tx = threadIdx.x & 31;
  const int ty = threadIdx.x >> 5;
  #pragma unroll
  for (int r = 0; r < 32; r += 8)
    tile[ty + r][tx] = src[(long)(kb + ty + r) * DQh + nb + tx];
  __syncthreads();
  #pragma unroll
  for (int r = 0; r < 32; r += 8)
    dst[(long)(nb + ty + r) * DIM + kb + tx] = f2bf(tile[tx][ty + r]);
}

__global__ __launch_bounds__(256)
void cast_bf16(const float* __restrict__ X, ushort_t* __restrict__ Yq)
{
  const long i = ((long)blockIdx.x * 256 + threadIdx.x) * 4;
  const float4 v = *(const float4*)(X + i);
  ushort4 sv = make_ushort4(f2bf(v.x), f2bf(v.y), f2bf(v.z), f2bf(v.w));
  *(ushort4*)(Yq + i) = sv;
}

// ---------------------------------------------------------------------------

extern "C" void kernel_launch(void* const* d_in, const int* in_sizes, int n_in,
                              void* d_out, int out_size, void* d_ws, size_t ws_size,
                              hipStream_t stream)
{
  (void)in_sizes; (void)n_in; (void)out_size; (void)ws_size;
  const float* mem = (const float*)d_in[0];
  const float* y0  = (const float*)d_in[1];
  const float* Wq1 = (const float*)d_in[2];
  const float* Wk1 = (const float*)d_in[3];
  const float* Wv1 = (const float*)d_in[4];
  const float* Wo1 = (const float*)d_in[5];
  const float* Wq2 = (const float*)d_in[6];
  const float* Wk2 = (const float*)d_in[7];
  const float* Wv2 = (const float*)d_in[8];
  const float* Wo2 = (const float*)d_in[9];
  const float* E1  = (const float*)d_in[10];
  const float* D1  = (const float*)d_in[11];
  const float* E2  = (const float*)d_in[12];
  const float* D2  = (const float*)d_in[13];
  const float* g1  = (const float*)d_in[14];
  const float* b1  = (const float*)d_in[15];
  const float* g2  = (const float*)d_in[16];
  const float* b2  = (const float*)d_in[17];
  const float* g3  = (const float*)d_in[18];
  const float* b3  = (const float*)d_in[19];

  char* ws = (char*)d_ws;
  const size_t MB = 1ull << 20;
  ushort_t* wkv1  = (ushort_t*)(ws + 0 * MB);    // [2048][1024] K|V phase1
  ushort_t* wq1t  = (ushort_t*)(ws + 4 * MB);    // [1024][1024]
  ushort_t* wkv2  = (ushort_t*)(ws + 6 * MB);    // [2048][1024]
  ushort_t* wq2t  = (ushort_t*)(ws + 10 * MB);
  ushort_t* wo1b  = (ushort_t*)(ws + 12 * MB);
  ushort_t* wo2b  = (ushort_t*)(ws + 14 * MB);
  ushort_t* e1b   = (ushort_t*)(ws + 16 * MB);
  ushort_t* d1b   = (ushort_t*)(ws + 17 * MB);
  ushort_t* e2b   = (ushort_t*)(ws + 18 * MB);
  ushort_t* d2b   = (ushort_t*)(ws + 19 * MB);
  ushort_t* y0b   = (ushort_t*)(ws + 20 * MB);   // 32 MB
  ushort_t* memb  = (ushort_t*)(ws + 52 * MB);   // 64 MB
  ushort_t* bn2   = (ushort_t*)(ws + 116 * MB);  // 16 MB (LFFN)
  ushort_t* kbuf  = (ushort_t*)(ws + 148 * MB);  // 64 MB
  ushort_t* vbuf  = (ushort_t*)(ws + 212 * MB);  // 64 MB
  ushort_t* amatT = (ushort_t*)(ws + 276 * MB);  // 4 MB
  ushort_t* attnb = (ushort_t*)(ws + 280 * MB);  // 32 MB
  float*    ybuf  = (float*)(ws + 312 * MB);     // 64 MB (f32 LN output)
  ushort_t* ybf   = (ushort_t*)(ws + 376 * MB);  // 32 MB (bf16 LN output)
  ushort_t* hbuf  = (ushort_t*)(ws + 408 * MB);  // 32 MB
  float*    pbuf  = (float*)(ws + 440 * MB);     // 32 MB
  ushort_t* bn1   = attnb;                       // reuse (16 MB)

  // ---- prep ----
  cast_bf16<<<16384, 256, 0, stream>>>(y0, y0b);
  cast_bf16<<<32768, 256, 0, stream>>>(mem, memb);
  transpose_cast<<<dim3(4, 32, 8), 256, 0, stream>>>(Wk1, wkv1);
  transpose_cast<<<dim3(4, 32, 8), 256, 0, stream>>>(Wv1, wkv1 + (1 << 20));
  transpose_cast<<<dim3(4, 32, 8), 256, 0, stream>>>(Wq1, wq1t);
  transpose_cast<<<dim3(4, 32, 8), 256, 0, stream>>>(Wk2, wkv2);
  transpose_cast<<<dim3(4, 32, 8), 256, 0, stream>>>(Wv2, wkv2 + (1 << 20));
  transpose_cast<<<dim3(4, 32, 8), 256, 0, stream>>>(Wq2, wq2t);
  cast_bf16<<<1024, 256, 0, stream>>>(Wo1, wo1b);
  cast_bf16<<<1024, 256, 0, stream>>>(Wo2, wo2b);
  cast_bf16<<<512, 256, 0, stream>>>(E1, e1b);
  cast_bf16<<<512, 256, 0, stream>>>(D1, d1b);
  cast_bf16<<<512, 256, 0, stream>>>(E2, e2b);
  cast_bf16<<<512, 256, 0, stream>>>(D2, d2b);

  // ---- phase 1: masked self linear-attention ----
  gemm_qkv<<<dim3(16, 128), 256, 0, stream>>>(
      y0b, wkv1, kbuf, vbuf, NB * ST, 2048, DIM, 10, /*sm K*/ 0b01);
  gemm_ktv<<<dim3(128, 2), 256, 0, stream>>>(kbuf, vbuf, pbuf, ST, 512);
  ktv_reduce<<<2048, 256, 0, stream>>>(pbuf, amatT, 2);
  fused_qa<true><<<dim3(8, 128), 256, 0, stream>>>(y0b, wq1t, amatT, attnb);
  gemm_ln<true><<<256, 512, 0, stream>>>(
      attnb, wo1b, y0, g1, b1, ybf, ybuf, 1024);
  // ---- phase 2: cross linear-attention ----
  gemm_qkv<<<dim3(16, 256), 256, 0, stream>>>(
      memb, wkv2, kbuf, vbuf, NB * SM, 2048, DIM, 11, 0b01);
  gemm_ktv<<<dim3(128, 4), 256, 0, stream>>>(kbuf, vbuf, pbuf, SM, 512);
  ktv_reduce<<<2048, 256, 0, stream>>>(pbuf, amatT, 4);
  fused_qa<false><<<dim3(8, 128), 256, 0, stream>>>(ybf, wq2t, amatT, attnb);
  gemm_ln<true><<<256, 512, 0, stream>>>(
      attnb, wo2b, ybuf, g2, b2, ybf, ybuf, 1024);
  // ---- phase 3: LFFN ----
  gemm_bb<ST_BF16><<<dim3(4, 128), 256, 0, stream>>>(
      ybf, e1b, bn1, NB * ST, 512, DIM);
  gemm_bb<ST_SWISH><<<dim3(8, 128), 256, 0, stream>>>(
      bn1, d1b, hbuf, NB * ST, DIM, 512);
  gemm_bb<ST_BF16><<<dim3(4, 128), 256, 0, stream>>>(
      hbuf, e2b, bn2, NB * ST, 512, DIM);
  gemm_ln<false><<<256, 512, 0, stream>>>(
      bn2, d2b, ybuf, g3, b3, nullptr, (float*)d_out, 512);
}

// Round 8
// 844.675 us; speedup vs baseline: 1.0865x; 1.0865x over previous
//
#include <hip/hip_runtime.h>
#include <hip/hip_bf16.h>

#define DEVI __device__ __forceinline__

typedef __bf16 bfrag __attribute__((ext_vector_type(8)));
typedef unsigned short us8 __attribute__((ext_vector_type(8)));
typedef float f32x4 __attribute__((ext_vector_type(4)));
typedef unsigned short ushort_t;

static constexpr int NB  = 16;
static constexpr int NH  = 8;
static constexpr int DIM = 1024;
static constexpr int DQh = 128;
static constexpr int ST  = 1024;
static constexpr int SM  = 2048;
static constexpr float INV_SCALE = 0.29730177875068026f; // 1 / 128^0.25
static constexpr float LN_EPS = 1e-5f;

DEVI ushort_t f2bf(float f) {
  __hip_bfloat16 h = __float2bfloat16(f);
  return __builtin_bit_cast(ushort_t, h);
}
DEVI float bf2f(ushort_t u) {
  return __bfloat162float(__builtin_bit_cast(__hip_bfloat16, u));
}
DEVI bfrag ldfrag(const ushort_t* p) {
  return __builtin_bit_cast(bfrag, *(const us8*)p);
}
DEVI void gl16(const ushort_t* g, ushort_t* l) {
  __builtin_amdgcn_global_load_lds(
      (const __attribute__((address_space(1))) void*)g,
      (__attribute__((address_space(3))) void*)l, 16, 0, 0);
}

enum { ST_BF16 = 0, ST_SWISH = 1, ST_F32RES = 2 };

// ---------------------------------------------------------------------------
// K/V projection GEMM with fused wave-local softmax. Stores to an s-blocked
// layout [z = h*16+b][S/8][128 d][8 s] (bf16) consumed only by gemm_ktv.
// 128x128 tile, 4 waves 4x1 (M); softmax over head dim is wave-local.
// ---------------------------------------------------------------------------
__global__ __launch_bounds__(256, 4)
void gemm_qkv(const ushort_t* __restrict__ A, const ushort_t* __restrict__ Bt,
              ushort_t* __restrict__ P0, ushort_t* __restrict__ P1,
              int M, int N, int K, int logS, int smflags)
{
  __shared__ ushort_t As[128][32];
  __shared__ ushort_t Bs[128][32];
  const int tid = threadIdx.x;
  int bx = blockIdx.x, by = blockIdx.y;
  {
    const int gx = gridDim.x;
    const int nwg = gx * gridDim.y;
    int bid = by * gx + bx;
    if ((nwg & 7) == 0) bid = (bid & 7) * (nwg >> 3) + (bid >> 3);  // XCD swizzle
    bx = bid % gx; by = bid / gx;
  }
  const int m0 = by * 128, n0 = bx * 128;

  const int lane = tid & 63;
  const int w = tid >> 6;
  const int wr = w * 32;
  const int frow = lane & 15;
  const int q = lane >> 4;

  const int grow = lane >> 2;
  const int gk = ((lane & 3) ^ ((lane >> 3) & 3)) * 8;
  const ushort_t* Ag = A + (long)(m0 + w * 32 + grow) * K + gk;
  const ushort_t* Bg = Bt + (long)(n0 + w * 32 + grow) * K + gk;

  f32x4 acc[2][8];
  #pragma unroll
  for (int i = 0; i < 2; ++i)
    #pragma unroll
    for (int j = 0; j < 8; ++j) acc[i][j] = f32x4{0.f, 0.f, 0.f, 0.f};

  const int kqs = (frow >> 1) & 3;
  for (int k0 = 0; k0 < K; k0 += 32) {
    __syncthreads();
    gl16(Ag + k0,                &As[w * 32][0]);
    gl16(Ag + k0 + (long)16 * K, &As[w * 32 + 16][0]);
    gl16(Bg + k0,                &Bs[w * 32][0]);
    gl16(Bg + k0 + (long)16 * K, &Bs[w * 32 + 16][0]);
    __syncthreads();
    const int kq = (q ^ kqs) * 8;
    const bfrag af0 = ldfrag(&As[wr + frow][kq]);
    const bfrag af1 = ldfrag(&As[wr + 16 + frow][kq]);
    #pragma unroll
    for (int j = 0; j < 8; ++j) {
      const bfrag bf = ldfrag(&Bs[j * 16 + frow][kq]);
      acc[0][j] = __builtin_amdgcn_mfma_f32_16x16x32_bf16(af0, bf, acc[0][j], 0, 0, 0);
      acc[1][j] = __builtin_amdgcn_mfma_f32_16x16x32_bf16(af1, bf, acc[1][j], 0, 0, 0);
    }
  }

  const int sel = n0 >> 10;  // block-uniform
  const bool dosm = (smflags >> sel) & 1;
  const int h = (n0 >> 7) & 7;
  ushort_t* __restrict__ Bq = (sel == 0) ? P0 : P1;
  const int S = 1 << logS;
  const int b_blk = m0 >> logS;          // constant per block (S >= 128)
  const int s_m0 = m0 & (S - 1);

  if (dosm) {
    #pragma unroll
    for (int i = 0; i < 2; ++i) {
      #pragma unroll
      for (int e = 0; e < 4; ++e) {
        float v[8];
        #pragma unroll
        for (int j = 0; j < 8; ++j) v[j] = acc[i][j][e] * INV_SCALE;
        float mx = v[0];
        #pragma unroll
        for (int j = 1; j < 8; ++j) mx = fmaxf(mx, v[j]);
        mx = fmaxf(mx, __shfl_xor(mx, 1));
        mx = fmaxf(mx, __shfl_xor(mx, 2));
        mx = fmaxf(mx, __shfl_xor(mx, 4));
        mx = fmaxf(mx, __shfl_xor(mx, 8));
        float sm = 0.f;
        #pragma unroll
        for (int j = 0; j < 8; ++j) { v[j] = __expf(v[j] - mx); sm += v[j]; }
        sm += __shfl_xor(sm, 1);
        sm += __shfl_xor(sm, 2);
        sm += __shfl_xor(sm, 4);
        sm += __shfl_xor(sm, 8);
        const float inv = 1.0f / sm;
        #pragma unroll
        for (int j = 0; j < 8; ++j) acc[i][j][e] = v[j] * inv;
      }
    }
  }

  // blocked store: addr = z*S*128 + (s>>3)*1024 + d*8 + (s&7); lane writes
  // ushort4 (e=0..3 -> s consecutive). 256B-contiguous per instruction.
  ushort_t* zbase = Bq + (long)(h * 16 + b_blk) * S * 128;
  #pragma unroll
  for (int i = 0; i < 2; ++i) {
    const int sb = s_m0 + wr + i * 16 + q * 4;
    ushort_t* rowb = zbase + (long)(sb >> 3) * 1024 + (sb & 7);
    #pragma unroll
    for (int j = 0; j < 8; ++j) {
      ushort4 o = make_ushort4(f2bf(acc[i][j][0]), f2bf(acc[i][j][1]),
                               f2bf(acc[i][j][2]), f2bf(acc[i][j][3]));
      *(ushort4*)(rowb + (j * 16 + frow) * 8) = o;
    }
  }
}

// ---------------------------------------------------------------------------
// Fused Q path (R6): scores -> wave-local softmax -> P@A -> scramble store.
// ---------------------------------------------------------------------------
template<bool MASKED>
__global__ __launch_bounds__(256, 3)
void fused_qa(const ushort_t* __restrict__ A, const ushort_t* __restrict__ Wq,
              const ushort_t* __restrict__ AT, ushort_t* __restrict__ Out)
{
  __shared__ ushort_t As[128][32];
  __shared__ ushort_t Bs[128][32];
  __shared__ ushort_t Ps[4][32][128];
  const int tid = threadIdx.x;
  int h = blockIdx.x, by = blockIdx.y;
  {
    const int gx = gridDim.x;
    const int nwg = gx * gridDim.y;
    int bid = by * gx + h;
    if ((nwg & 7) == 0) bid = (bid & 7) * (nwg >> 3) + (bid >> 3);
    h = bid % gx; by = bid / gx;
  }
  const int m0 = by * 128;

  const int lane = tid & 63;
  const int w = tid >> 6;
  const int wr = w * 32;
  const int frow = lane & 15;
  const int q = lane >> 4;

  const int grow = lane >> 2;
  const int gk = ((lane & 3) ^ ((lane >> 3) & 3)) * 8;
  const ushort_t* Ag = A + (long)(m0 + w * 32 + grow) * 1024 + gk;
  const ushort_t* Bg = Wq + (long)(h * 128 + w * 32 + grow) * 1024 + gk;

  f32x4 acc[2][8];
  #pragma unroll
  for (int i = 0; i < 2; ++i)
    #pragma unroll
    for (int j = 0; j < 8; ++j) acc[i][j] = f32x4{0.f, 0.f, 0.f, 0.f};

  const int kqs = (frow >> 1) & 3;
  for (int k0 = 0; k0 < 1024; k0 += 32) {
    __syncthreads();
    gl16(Ag + k0,             &As[w * 32][0]);
    gl16(Ag + k0 + 16 * 1024, &As[w * 32 + 16][0]);
    gl16(Bg + k0,             &Bs[w * 32][0]);
    gl16(Bg + k0 + 16 * 1024, &Bs[w * 32 + 16][0]);
    __syncthreads();
    const int kq = (q ^ kqs) * 8;
    const bfrag af0 = ldfrag(&As[wr + frow][kq]);
    const bfrag af1 = ldfrag(&As[wr + 16 + frow][kq]);
    #pragma unroll
    for (int j = 0; j < 8; ++j) {
      const bfrag bf = ldfrag(&Bs[j * 16 + frow][kq]);
      acc[0][j] = __builtin_amdgcn_mfma_f32_16x16x32_bf16(af0, bf, acc[0][j], 0, 0, 0);
      acc[1][j] = __builtin_amdgcn_mfma_f32_16x16x32_bf16(af1, bf, acc[1][j], 0, 0, 0);
    }
  }

  // softmax + write P to per-wave swizzled LDS
  #pragma unroll
  for (int i = 0; i < 2; ++i) {
    #pragma unroll
    for (int e = 0; e < 4; ++e) {
      const int row32 = i * 16 + q * 4 + e;
      const int srow = (m0 + wr + row32) & (ST - 1);
      float v[8];
      #pragma unroll
      for (int j = 0; j < 8; ++j) {
        v[j] = acc[i][j][e] * INV_SCALE;
        if (MASKED && (j * 16 + frow) > srow) v[j] = -3.0e38f;
      }
      float mx = v[0];
      #pragma unroll
      for (int j = 1; j < 8; ++j) mx = fmaxf(mx, v[j]);
      mx = fmaxf(mx, __shfl_xor(mx, 1));
      mx = fmaxf(mx, __shfl_xor(mx, 2));
      mx = fmaxf(mx, __shfl_xor(mx, 4));
      mx = fmaxf(mx, __shfl_xor(mx, 8));
      float sm = 0.f;
      #pragma unroll
      for (int j = 0; j < 8; ++j) { v[j] = __expf(v[j] - mx); sm += v[j]; }
      sm += __shfl_xor(sm, 1);
      sm += __shfl_xor(sm, 2);
      sm += __shfl_xor(sm, 4);
      sm += __shfl_xor(sm, 8);
      const float inv = 1.0f / sm;
      const int sw = (row32 >> 1) & 3;
      ushort_t* pr = &Ps[w][row32][0];
      #pragma unroll
      for (int j = 0; j < 8; ++j) {
        const int c = j * 16 + frow;
        const int pos = (c & ~31) | ((((c >> 3) & 3) ^ sw) << 3) | (c & 7);
        pr[pos] = f2bf(v[j] * inv);
      }
    }
  }

  // stage 2: P(128x128) @ AT_z(128e x 128d, [N][K] form)
  f32x4 acc2[2][8];
  #pragma unroll
  for (int i = 0; i < 2; ++i)
    #pragma unroll
    for (int j = 0; j < 8; ++j) acc2[i][j] = f32x4{0.f, 0.f, 0.f, 0.f};

  const ushort_t* Atg = AT + (long)((h << 4) + (m0 >> 10)) * 16384 +
                        (long)(w * 32 + grow) * 128 + gk;
  for (int d0 = 0; d0 < 128; d0 += 32) {
    __syncthreads();
    gl16(Atg + d0,            &Bs[w * 32][0]);
    gl16(Atg + d0 + 16 * 128, &Bs[w * 32 + 16][0]);
    __syncthreads();
    const int kq = (q ^ kqs) * 8;
    const bfrag af0 = ldfrag(&Ps[w][frow][d0 + kq]);
    const bfrag af1 = ldfrag(&Ps[w][16 + frow][d0 + kq]);
    #pragma unroll
    for (int j = 0; j < 8; ++j) {
      const bfrag bf = ldfrag(&Bs[j * 16 + frow][kq]);
      acc2[0][j] = __builtin_amdgcn_mfma_f32_16x16x32_bf16(af0, bf, acc2[0][j], 0, 0, 0);
      acc2[1][j] = __builtin_amdgcn_mfma_f32_16x16x32_bf16(af1, bf, acc2[1][j], 0, 0, 0);
    }
  }

  ushort_t* ob = Out + (long)(m0 >> 10) * (ST * DIM);
  #pragma unroll
  for (int i = 0; i < 2; ++i) {
    #pragma unroll
    for (int e = 0; e < 4; ++e) {
      const int srow = (m0 + wr + i * 16 + q * 4 + e) & (ST - 1);
      ushort_t* orow = ob + (long)(h * 128 + (srow >> 3)) * DIM + (srow & 7) * 128;
      #pragma unroll
      for (int j = 0; j < 8; ++j)
        orow[j * 16 + frow] = f2bf(acc2[i][j][e]);
    }
  }
}

// ---------------------------------------------------------------------------
// 128x128-tile bf16 GEMM (m97 structure), 2x2 waves. Epilogues:
//  ST_BF16 / ST_SWISH : bf16 store;  ST_F32RES: + f32 residual, f32 store.
// ---------------------------------------------------------------------------
template<int STORE>
__global__ __launch_bounds__(256, 2)
void gemm_bb(const ushort_t* __restrict__ A, const ushort_t* __restrict__ Bt,
             const float* __restrict__ Res,
             ushort_t* __restrict__ P0, float* __restrict__ Cf,
             int M, int N, int K)
{
  __shared__ ushort_t As[128][32];
  __shared__ ushort_t Bs[128][32];
  const int tid = threadIdx.x;
  int bx = blockIdx.x, by = blockIdx.y;
  {
    const int gx = gridDim.x;
    const int nwg = gx * gridDim.y;
    int bid = by * gx + bx;
    if ((nwg & 7) == 0) bid = (bid & 7) * (nwg >> 3) + (bid >> 3);
    bx = bid % gx; by = bid / gx;
  }
  const int m0 = by * 128, n0 = bx * 128;

  const int lane = tid & 63;
  const int w = tid >> 6;
  const int wr = (w >> 1) * 64, wc = (w & 1) * 64;
  const int frow = lane & 15;
  const int q = lane >> 4;

  const int grow = lane >> 2;
  const int gk = ((lane & 3) ^ ((lane >> 3) & 3)) * 8;
  const ushort_t* Ag = A + (long)(m0 + w * 32 + grow) * K + gk;
  const ushort_t* Bg = Bt + (long)(n0 + w * 32 + grow) * K + gk;

  f32x4 acc[4][4];
  #pragma unroll
  for (int i = 0; i < 4; ++i)
    #pragma unroll
    for (int j = 0; j < 4; ++j) acc[i][j] = f32x4{0.f, 0.f, 0.f, 0.f};

  const int kqs = (frow >> 1) & 3;
  for (int k0 = 0; k0 < K; k0 += 32) {
    __syncthreads();
    gl16(Ag + k0,                &As[w * 32][0]);
    gl16(Ag + k0 + (long)16 * K, &As[w * 32 + 16][0]);
    gl16(Bg + k0,                &Bs[w * 32][0]);
    gl16(Bg + k0 + (long)16 * K, &Bs[w * 32 + 16][0]);
    __syncthreads();
    const int kq = (q ^ kqs) * 8;
    bfrag af[4], bf[4];
    #pragma unroll
    for (int i = 0; i < 4; ++i) af[i] = ldfrag(&As[wr + i * 16 + frow][kq]);
    #pragma unroll
    for (int j = 0; j < 4; ++j) bf[j] = ldfrag(&Bs[wc + j * 16 + frow][kq]);
    #pragma unroll
    for (int i = 0; i < 4; ++i)
      #pragma unroll
      for (int j = 0; j < 4; ++j)
        acc[i][j] = __builtin_amdgcn_mfma_f32_16x16x32_bf16(af[i], bf[j], acc[i][j], 0, 0, 0);
  }

  const int rb = q * 4;
  #pragma unroll
  for (int i = 0; i < 4; ++i) {
    #pragma unroll
    for (int j = 0; j < 4; ++j) {
      #pragma unroll
      for (int e = 0; e < 4; ++e) {
        const int gm = m0 + wr + i * 16 + rb + e;
        const int gn = n0 + wc + j * 16 + frow;
        float val = acc[i][j][e];
        if constexpr (STORE == ST_SWISH) val = val / (1.0f + __expf(-val));
        if constexpr (STORE == ST_F32RES) {
          Cf[(long)gm * N + gn] = val + Res[(long)gm * N + gn];
        } else {
          P0[(long)gm * N + gn] = f2bf(val);
        }
      }
    }
  }
}

// ---------------------------------------------------------------------------
// Split-S K^T·V from the s-blocked layout: P[ch][z][e][d] =
// sum_{s in chunk} V[z][s][e] * softK[z][s][d]. gl16-staged, b128 frag reads.
// LDS per k-step: 4 s8-rows x [128][8] per operand.
// ---------------------------------------------------------------------------
__global__ __launch_bounds__(256, 2)
void gemm_ktv(const ushort_t* __restrict__ Kp, const ushort_t* __restrict__ Vp,
              float* __restrict__ P, int S, int SC)
{
  __shared__ ushort_t As[4096];   // V: [4 s8][128 e][8 s]
  __shared__ ushort_t Bs[4096];   // K: [4 s8][128 d][8 s]
  const int tid = threadIdx.x;
  const int z = blockIdx.x;
  const int ch = blockIdx.y;
  const int lane = tid & 63, w = tid >> 6;
  const int wr = (w >> 1) * 64, wc = (w & 1) * 64;
  const int frow = lane & 15, q = lane >> 4;
  const long zoff = (long)z * S * 128 + ((long)(ch * SC) >> 3) * 1024;
  const ushort_t* Vg = Vp + zoff + lane * 8;
  const ushort_t* Kg = Kp + zoff + lane * 8;

  f32x4 acc[4][4];
  #pragma unroll
  for (int i = 0; i < 4; ++i)
    #pragma unroll
    for (int j = 0; j < 4; ++j) acc[i][j] = f32x4{0.f, 0.f, 0.f, 0.f};

  for (int s0 = 0; s0 < SC; s0 += 32) {
    const long go = ((long)s0 >> 3) * 1024;
    __syncthreads();
    gl16(Vg + go + (2 * w) * 512,     &As[(2 * w) * 512]);
    gl16(Vg + go + (2 * w + 1) * 512, &As[(2 * w + 1) * 512]);
    gl16(Kg + go + (2 * w) * 512,     &Bs[(2 * w) * 512]);
    gl16(Kg + go + (2 * w + 1) * 512, &Bs[(2 * w + 1) * 512]);
    __syncthreads();
    bfrag af[4], bf[4];
    #pragma unroll
    for (int i = 0; i < 4; ++i)
      af[i] = ldfrag(&As[q * 1024 + (wr + i * 16 + frow) * 8]);
    #pragma unroll
    for (int j = 0; j < 4; ++j)
      bf[j] = ldfrag(&Bs[q * 1024 + (wc + j * 16 + frow) * 8]);
    #pragma unroll
    for (int i = 0; i < 4; ++i)
      #pragma unroll
      for (int j = 0; j < 4; ++j)
        acc[i][j] = __builtin_amdgcn_mfma_f32_16x16x32_bf16(af[i], bf[j], acc[i][j], 0, 0, 0);
  }
  float* Pz = P + ((long)ch * 128 + z) * 16384;
  const int rb = q * 4;
  #pragma unroll
  for (int i = 0; i < 4; ++i)
    #pragma unroll
    for (int j = 0; j < 4; ++j)
      #pragma unroll
      for (int e = 0; e < 4; ++e)
        Pz[(long)(wr + i * 16 + rb + e) * 128 + (wc + j * 16 + frow)] = acc[i][j][e];
}

__global__ __launch_bounds__(256)
void ktv_reduce(const float* __restrict__ P, ushort_t* __restrict__ AT, int nch)
{
  const long i = ((long)blockIdx.x * 256 + threadIdx.x) * 4;
  float4 s = *(const float4*)(P + i);
  for (int c = 1; c < nch; ++c) {
    const float4 v = *(const float4*)(P + (long)c * 2097152 + i);
    s.x += v.x; s.y += v.y; s.z += v.z; s.w += v.w;
  }
  ushort4 o = make_ushort4(f2bf(s.x), f2bf(s.y), f2bf(s.z), f2bf(s.w));
  *(ushort4*)(AT + i) = o;
}

// ---------------------------------------------------------------------------
// LayerNorm over DIM=1024, f32 in; f32 out (Y) + optional bf16 copy (Yb).
// ---------------------------------------------------------------------------
__global__ __launch_bounds__(256)
void layernorm_k(const float* __restrict__ X, const float* __restrict__ G,
                 const float* __restrict__ Bta, float* __restrict__ Y,
                 ushort_t* __restrict__ Yb)
{
  const int row = blockIdx.x;
  const int t = threadIdx.x;
  const float4 v = *(const float4*)(X + (long)row * DIM + t * 4);
  float s  = v.x + v.y + v.z + v.w;
  float sq = v.x * v.x + v.y * v.y + v.z * v.z + v.w * v.w;
  #pragma unroll
  for (int o = 32; o; o >>= 1) { s += __shfl_xor(s, o); sq += __shfl_xor(sq, o); }
  __shared__ float ps[4], pq[4];
  if ((t & 63) == 0) { ps[t >> 6] = s; pq[t >> 6] = sq; }
  __syncthreads();
  s  = ps[0] + ps[1] + ps[2] + ps[3];
  sq = pq[0] + pq[1] + pq[2] + pq[3];
  const float mean = s * (1.0f / DIM);
  const float var  = sq * (1.0f / DIM) - mean * mean;
  const float rstd = rsqrtf(var + LN_EPS);
  const float4 gv = *(const float4*)(G + t * 4);
  const float4 bv = *(const float4*)(Bta + t * 4);
  float4 o;
  o.x = (v.x - mean) * rstd * gv.x + bv.x;
  o.y = (v.y - mean) * rstd * gv.y + bv.y;
  o.z = (v.z - mean) * rstd * gv.z + bv.z;
  o.w = (v.w - mean) * rstd * gv.w + bv.w;
  *(float4*)(Y + (long)row * DIM + t * 4) = o;
  if (Yb) {
    ushort4 ob = make_ushort4(f2bf(o.x), f2bf(o.y), f2bf(o.z), f2bf(o.w));
    *(ushort4*)(Yb + (long)row * DIM + t * 4) = ob;
  }
}

__global__ __launch_bounds__(256)
void transpose_cast(const float* __restrict__ W, ushort_t* __restrict__ Wt)
{
  __shared__ float tile[32][33];
  const int z = blockIdx.z;
  const int kb = blockIdx.y * 32;
  const int nb = blockIdx.x * 32;
  const float* src = W + (long)z * DIM * DQh;
  ushort_t* dst = Wt + (long)z * DIM * DQh;
  const int tx = threadIdx.x & 31;
  const int ty = threadIdx.x >> 5;
  #pragma unroll
  for (int r = 0; r < 32; r += 8)
    tile[ty + r][tx] = src[(long)(kb + ty + r) * DQh + nb + tx];
  __syncthreads();
  #pragma unroll
  for (int r = 0; r < 32; r += 8)
    dst[(long)(nb + ty + r) * DIM + kb + tx] = f2bf(tile[tx][ty + r]);
}

__global__ __launch_bounds__(256)
void cast_bf16(const float* __restrict__ X, ushort_t* __restrict__ Yq)
{
  const long i = ((long)blockIdx.x * 256 + threadIdx.x) * 4;
  const float4 v = *(const float4*)(X + i);
  ushort4 sv = make_ushort4(f2bf(v.x), f2bf(v.y), f2bf(v.z), f2bf(v.w));
  *(ushort4*)(Yq + i) = sv;
}

// ---------------------------------------------------------------------------

extern "C" void kernel_launch(void* const* d_in, const int* in_sizes, int n_in,
                              void* d_out, int out_size, void* d_ws, size_t ws_size,
                              hipStream_t stream)
{
  (void)in_sizes; (void)n_in; (void)out_size; (void)ws_size;
  const float* mem = (const float*)d_in[0];
  const float* y0  = (const float*)d_in[1];
  const float* Wq1 = (const float*)d_in[2];
  const float* Wk1 = (const float*)d_in[3];
  const float* Wv1 = (const float*)d_in[4];
  const float* Wo1 = (const float*)d_in[5];
  const float* Wq2 = (const float*)d_in[6];
  const float* Wk2 = (const float*)d_in[7];
  const float* Wv2 = (const float*)d_in[8];
  const float* Wo2 = (const float*)d_in[9];
  const float* E1  = (const float*)d_in[10];
  const float* D1  = (const float*)d_in[11];
  const float* E2  = (const float*)d_in[12];
  const float* D2  = (const float*)d_in[13];
  const float* g1  = (const float*)d_in[14];
  const float* b1  = (const float*)d_in[15];
  const float* g2  = (const float*)d_in[16];
  const float* b2  = (const float*)d_in[17];
  const float* g3  = (const float*)d_in[18];
  const float* b3  = (const float*)d_in[19];

  char* ws = (char*)d_ws;
  const size_t MB = 1ull << 20;
  ushort_t* wkv1  = (ushort_t*)(ws + 0 * MB);    // [2048][1024] K|V phase1
  ushort_t* wq1t  = (ushort_t*)(ws + 4 * MB);    // [1024][1024]
  ushort_t* wkv2  = (ushort_t*)(ws + 6 * MB);    // [2048][1024]
  ushort_t* wq2t  = (ushort_t*)(ws + 10 * MB);
  ushort_t* wo1b  = (ushort_t*)(ws + 12 * MB);
  ushort_t* wo2b  = (ushort_t*)(ws + 14 * MB);
  ushort_t* e1b   = (ushort_t*)(ws + 16 * MB);
  ushort_t* d1b   = (ushort_t*)(ws + 17 * MB);
  ushort_t* e2b   = (ushort_t*)(ws + 18 * MB);
  ushort_t* d2b   = (ushort_t*)(ws + 19 * MB);
  ushort_t* y0b   = (ushort_t*)(ws + 20 * MB);   // 32 MB
  ushort_t* memb  = (ushort_t*)(ws + 52 * MB);   // 64 MB
  ushort_t* bn2   = (ushort_t*)(ws + 116 * MB);  // 16 MB (LFFN)
  ushort_t* kbuf  = (ushort_t*)(ws + 148 * MB);  // 64 MB (s-blocked)
  ushort_t* vbuf  = (ushort_t*)(ws + 212 * MB);  // 64 MB (s-blocked)
  ushort_t* amatT = (ushort_t*)(ws + 276 * MB);  // 4 MB
  ushort_t* attnb = (ushort_t*)(ws + 280 * MB);  // 32 MB
  float*    ybuf  = (float*)(ws + 312 * MB);     // 64 MB (f32 residual/LN)
  ushort_t* ybf   = (ushort_t*)(ws + 376 * MB);  // 32 MB
  ushort_t* hbuf  = (ushort_t*)(ws + 408 * MB);  // 32 MB
  float*    pbuf  = (float*)(ws + 440 * MB);     // 32 MB
  ushort_t* bn1   = attnb;                       // reuse (16 MB)

  // ---- prep ----
  cast_bf16<<<16384, 256, 0, stream>>>(y0, y0b);
  cast_bf16<<<32768, 256, 0, stream>>>(mem, memb);
  transpose_cast<<<dim3(4, 32, 8), 256, 0, stream>>>(Wk1, wkv1);
  transpose_cast<<<dim3(4, 32, 8), 256, 0, stream>>>(Wv1, wkv1 + (1 << 20));
  transpose_cast<<<dim3(4, 32, 8), 256, 0, stream>>>(Wq1, wq1t);
  transpose_cast<<<dim3(4, 32, 8), 256, 0, stream>>>(Wk2, wkv2);
  transpose_cast<<<dim3(4, 32, 8), 256, 0, stream>>>(Wv2, wkv2 + (1 << 20));
  transpose_cast<<<dim3(4, 32, 8), 256, 0, stream>>>(Wq2, wq2t);
  cast_bf16<<<1024, 256, 0, stream>>>(Wo1, wo1b);
  cast_bf16<<<1024, 256, 0, stream>>>(Wo2, wo2b);
  cast_bf16<<<512, 256, 0, stream>>>(E1, e1b);
  cast_bf16<<<512, 256, 0, stream>>>(D1, d1b);
  cast_bf16<<<512, 256, 0, stream>>>(E2, e2b);
  cast_bf16<<<512, 256, 0, stream>>>(D2, d2b);

  // ---- phase 1: masked self linear-attention ----
  gemm_qkv<<<dim3(16, 128), 256, 0, stream>>>(
      y0b, wkv1, kbuf, vbuf, NB * ST, 2048, DIM, 10, /*sm K*/ 0b01);
  gemm_ktv<<<dim3(128, 2), 256, 0, stream>>>(kbuf, vbuf, pbuf, ST, 512);
  ktv_reduce<<<2048, 256, 0, stream>>>(pbuf, amatT, 2);
  fused_qa<true><<<dim3(8, 128), 256, 0, stream>>>(y0b, wq1t, amatT, attnb);
  gemm_bb<ST_F32RES><<<dim3(8, 128), 256, 0, stream>>>(
      attnb, wo1b, y0, nullptr, ybuf, NB * ST, DIM, DIM);
  layernorm_k<<<NB * ST, 256, 0, stream>>>(ybuf, g1, b1, ybuf, ybf);

  // ---- phase 2: cross linear-attention ----
  gemm_qkv<<<dim3(16, 256), 256, 0, stream>>>(
      memb, wkv2, kbuf, vbuf, NB * SM, 2048, DIM, 11, 0b01);
  gemm_ktv<<<dim3(128, 4), 256, 0, stream>>>(kbuf, vbuf, pbuf, SM, 512);
  ktv_reduce<<<2048, 256, 0, stream>>>(pbuf, amatT, 4);
  fused_qa<false><<<dim3(8, 128), 256, 0, stream>>>(ybf, wq2t, amatT, attnb);
  gemm_bb<ST_F32RES><<<dim3(8, 128), 256, 0, stream>>>(
      attnb, wo2b, ybuf, nullptr, ybuf, NB * ST, DIM, DIM);
  layernorm_k<<<NB * ST, 256, 0, stream>>>(ybuf, g2, b2, ybuf, ybf);

  // ---- phase 3: LFFN ----
  gemm_bb<ST_BF16><<<dim3(4, 128), 256, 0, stream>>>(
      ybf, e1b, nullptr, bn1, nullptr, NB * ST, 512, DIM);
  gemm_bb<ST_SWISH><<<dim3(8, 128), 256, 0, stream>>>(
      bn1, d1b, nullptr, hbuf, nullptr, NB * ST, DIM, 512);
  gemm_bb<ST_BF16><<<dim3(4, 128), 256, 0, stream>>>(
      hbuf, e2b, nullptr, bn2, nullptr, NB * ST, 512, DIM);
  gemm_bb<ST_F32RES><<<dim3(8, 128), 256, 0, stream>>>(
      bn2, d2b, ybuf, nullptr, ybuf, NB * ST, DIM, 512);
  layernorm_k<<<NB * ST, 256, 0, stream>>>(ybuf, g3, b3, (float*)d_out, nullptr);
}